// Round 4
// baseline (120.296 us; speedup 1.0000x reference)
//
#include <hip/hip_runtime.h>

// B=4096, F0=39, D=16, L=(128,128), H1=64
// Round-18: LDS-staged B via global_load_lds, 4-buffer ring, counted vmcnt(2),
// raw s_barrier per chunk (T3/T4 pattern).  r14/r16/r17 invariant: 901 MB of
// issued B-load bytes at ~15.8 TB/s, cadence ~1250 cyc/chunk vs 512 MFMA --
// the register-ring depth never reached HW (compiler waitcnt collapses it to
// dist-1).  LDS staging decouples load completion from the consuming wave's
// scoreboard (2-cadence pipeline) AND halves issued bytes to 450 MB (stage
// once/block, wp-pair reads LDS).  Ring=4 keeps buf=(2+u)&3 compile-time in
// the unroll-1 o2 loop (20%4==0).
//  - mfma_f32_32x32x16_f16, M=32 = 2 batches x 16 d, N=128, K=(i,j) folded:
//    L0 upper-tri 30 chunks + L1 80 = 110.  Wave = 2 batch-pairs x 2 n-quarters.
// Layouts (verified): A: lane A[m=lane&31][k=(lane>>5)*8+t]; B: B[k=(lane>>5)*8+t][n=lane&31];
//  D: D[row=(r&3)+8*(r>>2)+4*(lane>>5)][col=lane&31]
// Repacked B (BYTES): ch*8192 + kh*4096 + cg*1024 + lane*16
//  L0 ch=0..29 (IG0/JG0): i=ig*4+kh*2+half, j=jg*8+t; folded (W'[i,j]=W[i,j]+W[j,i], j>i).
//  L1 ch=30+jg*5+ig: j=jg*4+kh*2+half, i=ig*8+t, zero-pad i>=39.  Total 901,120 B.
// Per-chunk schedule: vmcnt(2) [S(c) landed] -> s_barrier -> ds_read frags(c)
//   -> stage S(c+2) -> build A -> 8 MFMA.  Stage clamps data-chunk to 109 so
//   the in-flight count stays uniform (dead writes to never-read buffers).

typedef _Float16 h2    __attribute__((ext_vector_type(2)));
typedef _Float16 f16x8 __attribute__((ext_vector_type(8)));
typedef __attribute__((ext_vector_type(16))) float f32x16;

#define XBB 1160   // per-batch halfs in xsH: 16 rows * 72 + 8 skew (2320 B, 16-aligned)
#define L0C 30
#define NCH 110

__device__ __constant__ int IG0[L0C] = {0,0,0,0,0, 1,1,1,1,1, 2,2,2,2, 3,3,3,3, 4,4,4, 5,5,5, 6,6, 7,7, 8, 9};
__device__ __constant__ int JG0[L0C] = {0,1,2,3,4, 0,1,2,3,4, 1,2,3,4, 1,2,3,4, 2,3,4, 2,3,4, 3,4, 3,4, 4, 4};
#define IG0T(c) ((c)<5?0:(c)<10?1:(c)<14?2:(c)<18?3:(c)<21?4:(c)<24?5:(c)<26?6:(c)<28?7:(c)<29?8:9)
#define JG0T(c) ((c)<10?((c)%5):(c)<18?(((c)-10)%4+1):(c)<24?(((c)-18)%3+2):(c)<28?(((c)-24)%2+3):4)

// ---------------- weight repack (unchanged layout) ----------------
__global__ __launch_bounds__(256)
void CIN_repack(const float* __restrict__ f0, const float* __restrict__ f1,
                uint4* __restrict__ ws)
{
    const int tid  = blockIdx.x * 256 + threadIdx.x;   // 56320 total
    const int n    = tid & 127;
    const int slot = tid >> 7;
    const int half = slot & 1;
    const int kh   = (slot >> 1) & 1;
    const int ch   = slot >> 2;                         // 0..109
    float v[8];
    if (ch < L0C) {
        const int ig = IG0[ch], jg = JG0[ch];
        const int i = ig * 4 + kh * 2 + half;
#pragma unroll
        for (int t = 0; t < 8; ++t) {
            const int j = jg * 8 + t;
            float val = 0.f;
            if (i < 39 && j < 39 && j >= i) {
                val = f0[(i * 39 + j) * 128 + n];
                if (j > i) val += f0[(j * 39 + i) * 128 + n];
            }
            v[t] = val;
        }
    } else {
        const int c1 = ch - L0C;
        const int jg = c1 / 5, ig = c1 - jg * 5;
        const int j = jg * 4 + kh * 2 + half;
#pragma unroll
        for (int t = 0; t < 8; ++t) {
            const int i = ig * 8 + t;
            v[t] = (i < 39) ? f1[(i * 64 + j) * 128 + n] : 0.f;
        }
    }
    union { h2 h[4]; uint4 q; } pk;
#pragma unroll
    for (int t = 0; t < 4; ++t)
        pk.h[t] = h2{(_Float16)v[2 * t], (_Float16)v[2 * t + 1]};
    const int lane = half * 32 + (n & 31);
    const int cg   = n >> 5;
    ws[ch * 512 + kh * 256 + cg * 64 + lane] = pk.q;
}

// ---- main: grid 512, 8 batches/block, wave = 2 pairs x 2 n-quarters,
// ---- LDS-staged B (4-buffer ring, global_load_lds, counted vmcnt) ----
__global__ __launch_bounds__(256, 2)
void CIN_main(const float* __restrict__ x,
              const char* __restrict__ wsB,
              const float* __restrict__ dw,
              const float* __restrict__ db,
              float* __restrict__ out)
{
    __shared__ __align__(16) char bBc[4 * 8192];       // B chunk ring (32 KB)
    __shared__ __align__(16) _Float16 xsH[8 * XBB];    // [bb]: 16 rows of 72 (i<=39 used)
    __shared__ __align__(4)  _Float16 hsH[8][64][18];  // [bb][j][d]
    __shared__ float dws[192];
    __shared__ float red[4][4];

    const int tid  = threadIdx.x;
    const int w    = tid >> 6;
    const int wp   = w >> 1;       // batch-pair group: pairs {2wp, 2wp+1}
    const int wn   = w & 1;        // n-half: quarters {2wn, 2wn+1}
    const int lane = tid & 63;
    const int half = lane >> 5;
    const int d    = lane & 15;
    const int bsel = (lane >> 4) & 1;
    const int col  = lane & 31;

    // stage one 8KB chunk cooperatively: wave w covers bytes [w*2KB, w*2KB+2KB)
    auto stageB = [&](int ch, int buf) {
        const char* src = wsB + (size_t)ch * 8192 + w * 2048 + lane * 16;
        char* dst = bBc + buf * 8192 + w * 2048;
        __builtin_amdgcn_global_load_lds(
            (const __attribute__((address_space(1))) void*)(src),
            (__attribute__((address_space(3))) void*)(dst), 16, 0, 0);
        __builtin_amdgcn_global_load_lds(
            (const __attribute__((address_space(1))) void*)(src + 1024),
            (__attribute__((address_space(3))) void*)(dst + 1024), 16, 0, 0);
    };

    stageB(0, 0);                  // prime ring (drained by the x-staging syncthreads)
    stageB(1, 1);

    // ---- stage x for 8 batches as f16 (1248 float4, coalesced) ----
    const float4* xg4 = (const float4*)(x + (size_t)blockIdx.x * 8 * 624);
    for (int e4 = tid; e4 < 1248; e4 += 256) {
        float4 v = xg4[e4];
        int bb = e4 / 156, r = e4 - bb * 156;
        int i = r >> 2, d0 = (r & 3) * 4;
        _Float16* bp = xsH + bb * XBB + i;
        bp[(d0 + 0) * 72] = (_Float16)v.x; bp[(d0 + 1) * 72] = (_Float16)v.y;
        bp[(d0 + 2) * 72] = (_Float16)v.z; bp[(d0 + 3) * 72] = (_Float16)v.w;
    }
    if (tid < 128) { int bb = tid >> 4, dd = tid & 15; xsH[bb * XBB + dd * 72 + 39] = (_Float16)0.f; }
    if (tid < 192) dws[tid] = dw[tid];
    __syncthreads();

    const _Float16* xrow[2] = {
        xsH + ((wp * 2 + 0) * 2 + bsel) * XBB + d * 72,
        xsH + ((wp * 2 + 1) * 2 + bsel) * XBB + d * 72
    };

    // ---- xw: the 40 halfs of x[0..39] per lane-pair, REGISTERS, serve both layers ----
    h2 xw[2][20];
#pragma unroll
    for (int p = 0; p < 2; ++p)
#pragma unroll
        for (int w5 = 0; w5 < 5; ++w5) {
            union { f16x8 v; h2 h[4]; } u;
            u.v = *(const f16x8*)(xrow[p] + w5 * 8);    // one ds_read_b128
#pragma unroll
            for (int q = 0; q < 4; ++q) xw[p][w5 * 4 + q] = u.h[q];
        }

    f32x16 acc[2][2];              // [p][nq]
#pragma unroll
    for (int p = 0; p < 2; ++p)
#pragma unroll
        for (int nq = 0; nq < 2; ++nq)
#pragma unroll
            for (int r = 0; r < 16; ++r) acc[p][nq][r] = 0.f;

    h2 sp2[2][2];
    const char* bfr = bBc + wn * 2048 + (size_t)lane * 16;   // frag base (buf imm added per chunk)

    // ---------------- layer 0: 30 chunks, LDS ring, counted vmcnt ------
#pragma unroll
    for (int c = 0; c < L0C; ++c) {
        asm volatile("s_waitcnt vmcnt(2)" ::: "memory");   // S(c) landed in LDS
        __builtin_amdgcn_sched_barrier(0);
        __builtin_amdgcn_s_barrier();                      // everyone's S(c) landed
        const int ig = IG0T(c);
        const int jg = JG0T(c);
        if ((c == 0) || (IG0T(c) != IG0T(c - 1))) {
            // xi: i = ig*4 + kh*2 + half -> reg xw[p][ig*2+kh], element = half
#pragma unroll
            for (int p = 0; p < 2; ++p)
#pragma unroll
                for (int kh = 0; kh < 2; ++kh) {
                    const h2 pr = xw[p][ig * 2 + kh];
                    const _Float16 vv = half ? pr.y : pr.x;
                    sp2[p][kh] = h2{vv, vv};
                }
        }
        const char* bb = bfr + (c & 3) * 8192;
        const f16x8 B00 = *(const f16x8*)(bb);
        const f16x8 B01 = *(const f16x8*)(bb + 1024);
        const f16x8 B10 = *(const f16x8*)(bb + 4096);
        const f16x8 B11 = *(const f16x8*)(bb + 5120);
        stageB(c + 2, (c + 2) & 3);                        // c+2 <= 31
#pragma unroll
        for (int p = 0; p < 2; ++p) {
            union { h2 h[4]; f16x8 v; } a0, a1;
#pragma unroll
            for (int q = 0; q < 4; ++q) {
                a0.h[q] = sp2[p][0] * xw[p][jg * 4 + q];   // v_pk_mul_f16
                a1.h[q] = sp2[p][1] * xw[p][jg * 4 + q];
            }
            acc[p][0] = __builtin_amdgcn_mfma_f32_32x32x16_f16(a0.v, B00, acc[p][0], 0, 0, 0);
            acc[p][1] = __builtin_amdgcn_mfma_f32_32x32x16_f16(a0.v, B01, acc[p][1], 0, 0, 0);
            acc[p][0] = __builtin_amdgcn_mfma_f32_32x32x16_f16(a1.v, B10, acc[p][0], 0, 0, 0);
            acc[p][1] = __builtin_amdgcn_mfma_f32_32x32x16_f16(a1.v, B11, acc[p][1], 0, 0, 0);
        }
    }

    // ---------------- layer-0 epilogue ----------------
    float cs[4] = {0.f, 0.f, 0.f, 0.f};
    if (wn == 0) {
        // n 0..63 -> h
#pragma unroll
        for (int p = 0; p < 2; ++p)
#pragma unroll
            for (int nq = 0; nq < 2; ++nq)
#pragma unroll
                for (int r = 0; r < 16; r += 2) {
                    const int row = (r & 3) + 8 * (r >> 2) + 4 * half;
                    h2 pr = h2{(_Float16)fmaxf(acc[p][nq][r],     0.f),
                               (_Float16)fmaxf(acc[p][nq][r + 1], 0.f)};
                    *(h2*)&hsH[(wp * 2 + p) * 2 + (row >> 4)][nq * 32 + col][row & 15] = pr;
                }
    } else {
        // n 64..127 -> finals, dot dw rows (n-64)
#pragma unroll
        for (int nq = 0; nq < 2; ++nq) {
            const float dwv = dws[nq * 32 + col];
#pragma unroll
            for (int p = 0; p < 2; ++p)
#pragma unroll
                for (int r = 0; r < 16; ++r) {
                    const int row = (r & 3) + 8 * (r >> 2) + 4 * half;
                    cs[p * 2 + (row >> 4)] += fmaxf(acc[p][nq][r], 0.f) * dwv;
                }
        }
    }
#pragma unroll
    for (int p = 0; p < 2; ++p)
#pragma unroll
        for (int nq = 0; nq < 2; ++nq)
#pragma unroll
            for (int r = 0; r < 16; ++r) acc[p][nq][r] = 0.f;
    __syncthreads();   // h visible to all waves (also drains S(30),S(31) - ready)

    // -------- layer 1: 4 outer x 20 unrolled chunks (30..109), buf=(2+u)&3 ------
#pragma unroll 1
    for (int o2 = 0; o2 < 4; ++o2) {
#pragma unroll
        for (int u = 0; u < 20; ++u) {
            asm volatile("s_waitcnt vmcnt(2)" ::: "memory");
            __builtin_amdgcn_sched_barrier(0);
            __builtin_amdgcn_s_barrier();
            const int ig2 = u % 5;                 // window index, compile-time
            if (ig2 == 0) {
                const int jb = (o2 * 4 + u / 5) * 4;
#pragma unroll
                for (int p = 0; p < 2; ++p)
#pragma unroll
                    for (int kh = 0; kh < 2; ++kh) {
                        const _Float16 s = hsH[(wp * 2 + p) * 2 + bsel][jb + kh * 2 + half][d];
                        sp2[p][kh] = h2{s, s};
                    }
            }
            const char* bb = bfr + ((2 + u) & 3) * 8192;
            const f16x8 B00 = *(const f16x8*)(bb);
            const f16x8 B01 = *(const f16x8*)(bb + 1024);
            const f16x8 B10 = *(const f16x8*)(bb + 4096);
            const f16x8 B11 = *(const f16x8*)(bb + 5120);
            int chn = 30 + o2 * 20 + u + 2; if (chn > NCH - 1) chn = NCH - 1;  // clamp: dead re-stage keeps vmcnt uniform
            stageB(chn, u & 3);                    // (ch+2)&3 == u&3
#pragma unroll
            for (int p = 0; p < 2; ++p) {
                union { h2 h[4]; f16x8 v; } a0, a1;
#pragma unroll
                for (int q = 0; q < 4; ++q) {
                    a0.h[q] = sp2[p][0] * xw[p][ig2 * 4 + q];
                    a1.h[q] = sp2[p][1] * xw[p][ig2 * 4 + q];
                }
                acc[p][0] = __builtin_amdgcn_mfma_f32_32x32x16_f16(a0.v, B00, acc[p][0], 0, 0, 0);
                acc[p][1] = __builtin_amdgcn_mfma_f32_32x32x16_f16(a0.v, B01, acc[p][1], 0, 0, 0);
                acc[p][0] = __builtin_amdgcn_mfma_f32_32x32x16_f16(a1.v, B10, acc[p][0], 0, 0, 0);
                acc[p][1] = __builtin_amdgcn_mfma_f32_32x32x16_f16(a1.v, B11, acc[p][1], 0, 0, 0);
            }
        }
    }

    // ---------------- layer-1 epilogue + reduction ----------------
#pragma unroll
    for (int nq = 0; nq < 2; ++nq) {
        const float dwv = dws[64 + (wn * 2 + nq) * 32 + col];
#pragma unroll
        for (int p = 0; p < 2; ++p)
#pragma unroll
            for (int r = 0; r < 16; ++r) {
                const int row = (r & 3) + 8 * (r >> 2) + 4 * half;
                cs[p * 2 + (row >> 4)] += fmaxf(acc[p][nq][r], 0.f) * dwv;
            }
    }
#pragma unroll
    for (int rr = 0; rr < 4; ++rr)
#pragma unroll
        for (int off = 32; off > 0; off >>= 1)
            cs[rr] += __shfl_xor(cs[rr], off, 64);
    if (lane == 0) {
#pragma unroll
        for (int rr = 0; rr < 4; ++rr) red[w][rr] = cs[rr];
    }
    __syncthreads();
    // block batch bb = wp*4 + l (l = cs index); sum the two n-halves
    if (tid < 8) {
        const int wpp = tid >> 2, l = tid & 3;
        out[blockIdx.x * 8 + tid] = red[wpp * 2][l] + red[wpp * 2 + 1][l] + db[0];
    }
}

extern "C" void kernel_launch(void* const* d_in, const int* in_sizes, int n_in,
                              void* d_out, int out_size, void* d_ws, size_t ws_size,
                              hipStream_t stream)
{
    const float* x  = (const float*)d_in[0];
    const float* f0 = (const float*)d_in[1];
    const float* f1 = (const float*)d_in[2];
    const float* dw = (const float*)d_in[3];
    const float* db = (const float*)d_in[4];
    float* out = (float*)d_out;

    CIN_repack<<<dim3(220), dim3(256), 0, stream>>>(f0, f1, (uint4*)d_ws);
    CIN_main<<<dim3(512), dim3(256), 0, stream>>>(x, (const char*)d_ws, dw, db, out);
}

// Round 5
// 118.220 us; speedup vs baseline: 1.0176x; 1.0176x over previous
//
#include <hip/hip_runtime.h>

// B=4096, F0=39, D=16, L=(128,128), H1=64
// Round-19: r18 + TIGHT-ROLLED layer-1 (outer jgrp 0..15 rolled, inner ig 0..4
// unrolled; body ~1.3KB, 16 iterations).  r14-r18 elimination table: cadence
// pinned at ~1250 cyc/SIMD/chunk across reg-ring dist-2/4, +-barrier, LDS ring
// w/ counted vmcnt, 2 AND 4 waves/SIMD, 16KB and 8KB issued B-bytes/chunk.
// Loads/LDS/VALU-issue/TLP eliminated.  Invariant: ~35KB unrolled straight-line
// K-loop code streaming through the 32KB L1I (shared per 2 CUs) -- I-fetch is
// the one shared resource extra waves can't hide (explains r14's 4-wave null).
// This round makes 73% of chunks run from a warm 1.3KB body; L0 (27%) stays
// straight-line.  Everything else byte-identical to r18.
//  - mfma_f32_32x32x16_f16, M=32 = 2 batches x 16 d, N=128, K=(i,j) folded:
//    L0 upper-tri 30 chunks + L1 80 = 110.  Wave = 2 batch-pairs x 2 n-quarters.
// Layouts (verified): A: lane A[m=lane&31][k=(lane>>5)*8+t]; B: B[k=(lane>>5)*8+t][n=lane&31];
//  D: D[row=(r&3)+8*(r>>2)+4*(lane>>5)][col=lane&31]
// Repacked B (BYTES): ch*8192 + kh*4096 + cg*1024 + lane*16
//  L0 ch=0..29 (IG0/JG0): i=ig*4+kh*2+half, j=jg*8+t; folded (W'[i,j]=W[i,j]+W[j,i], j>i).
//  L1 ch=30+jg*5+ig: j=jg*4+kh*2+half, i=ig*8+t, zero-pad i>=39.  Total 901,120 B.
// Per-chunk schedule: vmcnt(2) [S(c) landed] -> s_barrier -> ds_read frags(c)
//   -> stage S(c+2) -> build A -> 8 MFMA.  Stage clamps data-chunk to 109 but
//   keeps buf=(ch+2)&3 so the in-flight count stays uniform.

typedef _Float16 h2    __attribute__((ext_vector_type(2)));
typedef _Float16 f16x8 __attribute__((ext_vector_type(8)));
typedef __attribute__((ext_vector_type(16))) float f32x16;

#define XBB 1160   // per-batch halfs in xsH: 16 rows * 72 + 8 skew (2320 B, 16-aligned)
#define L0C 30
#define NCH 110

__device__ __constant__ int IG0[L0C] = {0,0,0,0,0, 1,1,1,1,1, 2,2,2,2, 3,3,3,3, 4,4,4, 5,5,5, 6,6, 7,7, 8, 9};
__device__ __constant__ int JG0[L0C] = {0,1,2,3,4, 0,1,2,3,4, 1,2,3,4, 1,2,3,4, 2,3,4, 2,3,4, 3,4, 3,4, 4, 4};
#define IG0T(c) ((c)<5?0:(c)<10?1:(c)<14?2:(c)<18?3:(c)<21?4:(c)<24?5:(c)<26?6:(c)<28?7:(c)<29?8:9)
#define JG0T(c) ((c)<10?((c)%5):(c)<18?(((c)-10)%4+1):(c)<24?(((c)-18)%3+2):(c)<28?(((c)-24)%2+3):4)

// ---------------- weight repack (unchanged layout) ----------------
__global__ __launch_bounds__(256)
void CIN_repack(const float* __restrict__ f0, const float* __restrict__ f1,
                uint4* __restrict__ ws)
{
    const int tid  = blockIdx.x * 256 + threadIdx.x;   // 56320 total
    const int n    = tid & 127;
    const int slot = tid >> 7;
    const int half = slot & 1;
    const int kh   = (slot >> 1) & 1;
    const int ch   = slot >> 2;                         // 0..109
    float v[8];
    if (ch < L0C) {
        const int ig = IG0[ch], jg = JG0[ch];
        const int i = ig * 4 + kh * 2 + half;
#pragma unroll
        for (int t = 0; t < 8; ++t) {
            const int j = jg * 8 + t;
            float val = 0.f;
            if (i < 39 && j < 39 && j >= i) {
                val = f0[(i * 39 + j) * 128 + n];
                if (j > i) val += f0[(j * 39 + i) * 128 + n];
            }
            v[t] = val;
        }
    } else {
        const int c1 = ch - L0C;
        const int jg = c1 / 5, ig = c1 - jg * 5;
        const int j = jg * 4 + kh * 2 + half;
#pragma unroll
        for (int t = 0; t < 8; ++t) {
            const int i = ig * 8 + t;
            v[t] = (i < 39) ? f1[(i * 64 + j) * 128 + n] : 0.f;
        }
    }
    union { h2 h[4]; uint4 q; } pk;
#pragma unroll
    for (int t = 0; t < 4; ++t)
        pk.h[t] = h2{(_Float16)v[2 * t], (_Float16)v[2 * t + 1]};
    const int lane = half * 32 + (n & 31);
    const int cg   = n >> 5;
    ws[ch * 512 + kh * 256 + cg * 64 + lane] = pk.q;
}

// ---- main: grid 512, 8 batches/block, wave = 2 pairs x 2 n-quarters,
// ---- LDS-staged B (4-buffer ring, global_load_lds, counted vmcnt),
// ---- L1 tight-rolled (16 x unrolled-5) ----
__global__ __launch_bounds__(256, 2)
void CIN_main(const float* __restrict__ x,
              const char* __restrict__ wsB,
              const float* __restrict__ dw,
              const float* __restrict__ db,
              float* __restrict__ out)
{
    __shared__ __align__(16) char bBc[4 * 8192];       // B chunk ring (32 KB)
    __shared__ __align__(16) _Float16 xsH[8 * XBB];    // [bb]: 16 rows of 72 (i<=39 used)
    __shared__ __align__(4)  _Float16 hsH[8][64][18];  // [bb][j][d]
    __shared__ float dws[192];
    __shared__ float red[4][4];

    const int tid  = threadIdx.x;
    const int w    = tid >> 6;
    const int wp   = w >> 1;       // batch-pair group: pairs {2wp, 2wp+1}
    const int wn   = w & 1;        // n-half: quarters {2wn, 2wn+1}
    const int lane = tid & 63;
    const int half = lane >> 5;
    const int d    = lane & 15;
    const int bsel = (lane >> 4) & 1;
    const int col  = lane & 31;

    // stage one 8KB chunk cooperatively: wave w covers bytes [w*2KB, w*2KB+2KB)
    auto stageB = [&](int ch, int buf) {
        const char* src = wsB + (size_t)ch * 8192 + w * 2048 + lane * 16;
        char* dst = bBc + buf * 8192 + w * 2048;
        __builtin_amdgcn_global_load_lds(
            (const __attribute__((address_space(1))) void*)(src),
            (__attribute__((address_space(3))) void*)(dst), 16, 0, 0);
        __builtin_amdgcn_global_load_lds(
            (const __attribute__((address_space(1))) void*)(src + 1024),
            (__attribute__((address_space(3))) void*)(dst + 1024), 16, 0, 0);
    };

    stageB(0, 0);                  // prime ring (drained by the x-staging syncthreads)
    stageB(1, 1);

    // ---- stage x for 8 batches as f16 (1248 float4, coalesced) ----
    const float4* xg4 = (const float4*)(x + (size_t)blockIdx.x * 8 * 624);
    for (int e4 = tid; e4 < 1248; e4 += 256) {
        float4 v = xg4[e4];
        int bb = e4 / 156, r = e4 - bb * 156;
        int i = r >> 2, d0 = (r & 3) * 4;
        _Float16* bp = xsH + bb * XBB + i;
        bp[(d0 + 0) * 72] = (_Float16)v.x; bp[(d0 + 1) * 72] = (_Float16)v.y;
        bp[(d0 + 2) * 72] = (_Float16)v.z; bp[(d0 + 3) * 72] = (_Float16)v.w;
    }
    if (tid < 128) { int bb = tid >> 4, dd = tid & 15; xsH[bb * XBB + dd * 72 + 39] = (_Float16)0.f; }
    if (tid < 192) dws[tid] = dw[tid];
    __syncthreads();

    const _Float16* xrow[2] = {
        xsH + ((wp * 2 + 0) * 2 + bsel) * XBB + d * 72,
        xsH + ((wp * 2 + 1) * 2 + bsel) * XBB + d * 72
    };

    // ---- xw: the 40 halfs of x[0..39] per lane-pair, REGISTERS, serve both layers ----
    h2 xw[2][20];
#pragma unroll
    for (int p = 0; p < 2; ++p)
#pragma unroll
        for (int w5 = 0; w5 < 5; ++w5) {
            union { f16x8 v; h2 h[4]; } u;
            u.v = *(const f16x8*)(xrow[p] + w5 * 8);    // one ds_read_b128
#pragma unroll
            for (int q = 0; q < 4; ++q) xw[p][w5 * 4 + q] = u.h[q];
        }

    f32x16 acc[2][2];              // [p][nq]
#pragma unroll
    for (int p = 0; p < 2; ++p)
#pragma unroll
        for (int nq = 0; nq < 2; ++nq)
#pragma unroll
            for (int r = 0; r < 16; ++r) acc[p][nq][r] = 0.f;

    h2 sp2[2][2];
    const char* bfr = bBc + wn * 2048 + (size_t)lane * 16;   // frag base (buf offset added per chunk)

    // ---------------- layer 0: 30 chunks, LDS ring, counted vmcnt ------
#pragma unroll
    for (int c = 0; c < L0C; ++c) {
        asm volatile("s_waitcnt vmcnt(2)" ::: "memory");   // S(c) landed in LDS
        __builtin_amdgcn_sched_barrier(0);
        __builtin_amdgcn_s_barrier();                      // everyone's S(c) landed
        const int ig = IG0T(c);
        const int jg = JG0T(c);
        if ((c == 0) || (IG0T(c) != IG0T(c - 1))) {
            // xi: i = ig*4 + kh*2 + half -> reg xw[p][ig*2+kh], element = half
#pragma unroll
            for (int p = 0; p < 2; ++p)
#pragma unroll
                for (int kh = 0; kh < 2; ++kh) {
                    const h2 pr = xw[p][ig * 2 + kh];
                    const _Float16 vv = half ? pr.y : pr.x;
                    sp2[p][kh] = h2{vv, vv};
                }
        }
        const char* bb = bfr + (c & 3) * 8192;
        const f16x8 B00 = *(const f16x8*)(bb);
        const f16x8 B01 = *(const f16x8*)(bb + 1024);
        const f16x8 B10 = *(const f16x8*)(bb + 4096);
        const f16x8 B11 = *(const f16x8*)(bb + 5120);
        stageB(c + 2, (c + 2) & 3);                        // c+2 <= 31
#pragma unroll
        for (int p = 0; p < 2; ++p) {
            union { h2 h[4]; f16x8 v; } a0, a1;
#pragma unroll
            for (int q = 0; q < 4; ++q) {
                a0.h[q] = sp2[p][0] * xw[p][jg * 4 + q];   // v_pk_mul_f16
                a1.h[q] = sp2[p][1] * xw[p][jg * 4 + q];
            }
            acc[p][0] = __builtin_amdgcn_mfma_f32_32x32x16_f16(a0.v, B00, acc[p][0], 0, 0, 0);
            acc[p][1] = __builtin_amdgcn_mfma_f32_32x32x16_f16(a0.v, B01, acc[p][1], 0, 0, 0);
            acc[p][0] = __builtin_amdgcn_mfma_f32_32x32x16_f16(a1.v, B10, acc[p][0], 0, 0, 0);
            acc[p][1] = __builtin_amdgcn_mfma_f32_32x32x16_f16(a1.v, B11, acc[p][1], 0, 0, 0);
        }
    }

    // ---------------- layer-0 epilogue ----------------
    float cs[4] = {0.f, 0.f, 0.f, 0.f};
    if (wn == 0) {
        // n 0..63 -> h
#pragma unroll
        for (int p = 0; p < 2; ++p)
#pragma unroll
            for (int nq = 0; nq < 2; ++nq)
#pragma unroll
                for (int r = 0; r < 16; r += 2) {
                    const int row = (r & 3) + 8 * (r >> 2) + 4 * half;
                    h2 pr = h2{(_Float16)fmaxf(acc[p][nq][r],     0.f),
                               (_Float16)fmaxf(acc[p][nq][r + 1], 0.f)};
                    *(h2*)&hsH[(wp * 2 + p) * 2 + (row >> 4)][nq * 32 + col][row & 15] = pr;
                }
    } else {
        // n 64..127 -> finals, dot dw rows (n-64)
#pragma unroll
        for (int nq = 0; nq < 2; ++nq) {
            const float dwv = dws[nq * 32 + col];
#pragma unroll
            for (int p = 0; p < 2; ++p)
#pragma unroll
                for (int r = 0; r < 16; ++r) {
                    const int row = (r & 3) + 8 * (r >> 2) + 4 * half;
                    cs[p * 2 + (row >> 4)] += fmaxf(acc[p][nq][r], 0.f) * dwv;
                }
        }
    }
#pragma unroll
    for (int p = 0; p < 2; ++p)
#pragma unroll
        for (int nq = 0; nq < 2; ++nq)
#pragma unroll
            for (int r = 0; r < 16; ++r) acc[p][nq][r] = 0.f;
    __syncthreads();   // h visible to all waves (also drains S(30),S(31) - ready)

    // -------- layer 1: 16 rolled jgrp x 5 unrolled ig (chunks 30..109) ------
    //          body ~1.3KB -> L1I-resident; buf = ch&3 (runtime, addr-only)
#pragma unroll 1
    for (int jgrp = 0; jgrp < 16; ++jgrp) {
        const int jb  = jgrp * 4;
        const int chb = 30 + jgrp * 5;          // base chunk of this group
        // sp2 from hsH (runtime jb -- LDS-addressed, no register indexing)
#pragma unroll
        for (int p = 0; p < 2; ++p)
#pragma unroll
            for (int kh = 0; kh < 2; ++kh) {
                const _Float16 s = hsH[(wp * 2 + p) * 2 + bsel][jb + kh * 2 + half][d];
                sp2[p][kh] = h2{s, s};
            }
#pragma unroll
        for (int ig2 = 0; ig2 < 5; ++ig2) {
            asm volatile("s_waitcnt vmcnt(2)" ::: "memory");
            __builtin_amdgcn_sched_barrier(0);
            __builtin_amdgcn_s_barrier();
            const int ch = chb + ig2;
            const char* bb = bfr + (size_t)((ch & 3) * 8192);
            const f16x8 B00 = *(const f16x8*)(bb);
            const f16x8 B01 = *(const f16x8*)(bb + 1024);
            const f16x8 B10 = *(const f16x8*)(bb + 4096);
            const f16x8 B11 = *(const f16x8*)(bb + 5120);
            int chn = ch + 2; const int bufn = chn & 3;
            if (chn > NCH - 1) chn = NCH - 1;   // clamp data, keep buf accounting uniform
            stageB(chn, bufn);
#pragma unroll
            for (int p = 0; p < 2; ++p) {
                union { h2 h[4]; f16x8 v; } a0, a1;
#pragma unroll
                for (int q = 0; q < 4; ++q) {
                    a0.h[q] = sp2[p][0] * xw[p][ig2 * 4 + q];
                    a1.h[q] = sp2[p][1] * xw[p][ig2 * 4 + q];
                }
                acc[p][0] = __builtin_amdgcn_mfma_f32_32x32x16_f16(a0.v, B00, acc[p][0], 0, 0, 0);
                acc[p][1] = __builtin_amdgcn_mfma_f32_32x32x16_f16(a0.v, B01, acc[p][1], 0, 0, 0);
                acc[p][0] = __builtin_amdgcn_mfma_f32_32x32x16_f16(a1.v, B10, acc[p][0], 0, 0, 0);
                acc[p][1] = __builtin_amdgcn_mfma_f32_32x32x16_f16(a1.v, B11, acc[p][1], 0, 0, 0);
            }
        }
    }

    // ---------------- layer-1 epilogue + reduction ----------------
#pragma unroll
    for (int nq = 0; nq < 2; ++nq) {
        const float dwv = dws[64 + (wn * 2 + nq) * 32 + col];
#pragma unroll
        for (int p = 0; p < 2; ++p)
#pragma unroll
            for (int r = 0; r < 16; ++r) {
                const int row = (r & 3) + 8 * (r >> 2) + 4 * half;
                cs[p * 2 + (row >> 4)] += fmaxf(acc[p][nq][r], 0.f) * dwv;
            }
    }
#pragma unroll
    for (int rr = 0; rr < 4; ++rr)
#pragma unroll
        for (int off = 32; off > 0; off >>= 1)
            cs[rr] += __shfl_xor(cs[rr], off, 64);
    if (lane == 0) {
#pragma unroll
        for (int rr = 0; rr < 4; ++rr) red[w][rr] = cs[rr];
    }
    __syncthreads();
    // block batch bb = wp*4 + l (l = cs index); sum the two n-halves
    if (tid < 8) {
        const int wpp = tid >> 2, l = tid & 3;
        out[blockIdx.x * 8 + tid] = red[wpp * 2][l] + red[wpp * 2 + 1][l] + db[0];
    }
}

extern "C" void kernel_launch(void* const* d_in, const int* in_sizes, int n_in,
                              void* d_out, int out_size, void* d_ws, size_t ws_size,
                              hipStream_t stream)
{
    const float* x  = (const float*)d_in[0];
    const float* f0 = (const float*)d_in[1];
    const float* f1 = (const float*)d_in[2];
    const float* dw = (const float*)d_in[3];
    const float* db = (const float*)d_in[4];
    float* out = (float*)d_out;

    CIN_repack<<<dim3(220), dim3(256), 0, stream>>>(f0, f1, (uint4*)d_ws);
    CIN_main<<<dim3(512), dim3(256), 0, stream>>>(x, (const char*)d_ws, dw, db, out);
}